// Round 9
// baseline (1152.350 us; speedup 1.0000x reference)
//
#include <hip/hip_runtime.h>
#include <math.h>

#define B_  2
#define S_  1024
#define H_  4096
#define NH_ 32
#define HD_ 128
#define I_  11008
#define R_  2048   // B*S tokens

typedef __attribute__((ext_vector_type(4))) int i32x4;
typedef __attribute__((ext_vector_type(4))) float f32x4;
typedef __attribute__((ext_vector_type(8))) short bf16x8;

// Tiled int8 layout v2 (matches gemm_i8p's LDS image exactly):
//  A-side (row-blocks of 256): tile (rb,kt) = 32 KB at ((rb*nk128+kt)<<15),
//    inside: [half h=row>>7][subk s=(k>>6)&1][kgrp (k>>4)&3][row&127][16B]
//  B-side (col-blocks of 128): tile (cb,kt) = 16 KB at ((cb*nk128+kt)<<14),
//    inside: [subk][kgrp][col&127][16B]
// Staging is contiguous 1KB chunks; frag reads are conflict-free.

// ---------------------------------------------------------------------------
// global->LDS DMA. r7 LESSON: the GLOBAL src address is PER-LANE (must include
// lane*16); the LDS dest is wave-uniform, HW adds lane*16.
__device__ __forceinline__ void gload_lds16(const void* g, void* l) {
    __builtin_amdgcn_global_load_lds(
        (const __attribute__((address_space(1))) unsigned int*)g,
        (__attribute__((address_space(3))) unsigned int*)l, 16, 0, 0);
}

__device__ __forceinline__ unsigned short f2bf(float f) {
    unsigned int u = __float_as_uint(f);
    u += 0x7fffu + ((u >> 16) & 1u);   // RNE
    return (unsigned short)(u >> 16);
}

// ---------------------------------------------------------------------------
// Pack one W (int32 [N][K]) into tiled-i8 v2 B-layout. Grid: (K/128, N/128).
__global__ __launch_bounds__(256)
void packW_k(const int* __restrict__ W, signed char* __restrict__ out, const int K)
{
    const int kt = blockIdx.x, cb = blockIdx.y, nk = gridDim.x;
    const int t = threadIdx.x;
    int* otile = (int*)(out + ((long)(cb * nk + kt) << 14));
#pragma unroll
    for (int i = 0; i < 16; ++i) {
        const int o = i * 256 + t;                 // int32 index in 16KB tile
        const int s = o >> 11, kg = (o >> 9) & 3, col = (o >> 2) & 127, jj = o & 3;
        const int4 w4 = *(const int4*)(W + (long)(cb * 128 + col) * K
                                         + kt * 128 + s * 64 + kg * 16 + jj * 4);
        otile[o] = (w4.x & 255) | ((w4.y & 255) << 8) | ((w4.z & 255) << 16) | (w4.w << 24);
    }
}

// ---------------------------------------------------------------------------
// RMSNorm + int8 quant (scale folded into w). Output in tiled-i8 v2 A-layout
// (K = H, nk128 = 32).
__global__ __launch_bounds__(256)
void rmsnorm_quant_k(const float* __restrict__ x, const float* __restrict__ w,
                     signed char* __restrict__ out)
{
    __shared__ float red[4];
    const int tid = threadIdx.x;
    const long row = blockIdx.x;
    const float4* xr = (const float4*)(x + row * H_);
    float4 xv[4];
    float ss = 0.f;
#pragma unroll
    for (int i = 0; i < 4; ++i) {
        xv[i] = xr[tid + i * 256];
        ss += xv[i].x * xv[i].x + xv[i].y * xv[i].y
            + xv[i].z * xv[i].z + xv[i].w * xv[i].w;
    }
#pragma unroll
    for (int off = 32; off; off >>= 1) ss += __shfl_xor(ss, off);
    if ((tid & 63) == 0) red[tid >> 6] = ss;
    __syncthreads();
    const float tot = red[0] + red[1] + red[2] + red[3];
    const float sc = 1.f / sqrtf(tot * (1.f / (float)H_) + 1e-6f);
    const float4* wr = (const float4*)w;
    int* ob = (int*)out;
    const long rb = row >> 8;
    const int hh = (int)((row >> 7) & 1);
    const int rr = (int)(row & 127);
#pragma unroll
    for (int i = 0; i < 4; ++i) {
        const float4 wv = wr[tid + i * 256];
        const int b0 = (int)fminf(fmaxf(rintf(xv[i].x * sc * wv.x), -128.f), 127.f);
        const int b1 = (int)fminf(fmaxf(rintf(xv[i].y * sc * wv.y), -128.f), 127.f);
        const int b2 = (int)fminf(fmaxf(rintf(xv[i].z * sc * wv.z), -128.f), 127.f);
        const int b3 = (int)fminf(fmaxf(rintf(xv[i].w * sc * wv.w), -128.f), 127.f);
        const int packed = (b0 & 255) | ((b1 & 255) << 8) | ((b2 & 255) << 16) | (b3 << 24);
        const int j4 = tid + i * 256;              // int32 group within row
        const int kt = j4 >> 5, sf = (j4 >> 4) & 1, kg = (j4 >> 2) & 3, jj = j4 & 3;
        const long a32 = ((rb * 32 + kt) << 13) + (hh << 12) + (sf << 11)
                       + (kg << 9) + (rr << 2) + jj;
        ob[a32] = packed;
    }
}

// ---------------------------------------------------------------------------
// int8 GEMM, 4-phase interleaved schedule (m201/m218 port): BM=256, BN=128,
// K-tile=128, 512 threads = 8 waves (4M x 2N), wave-out 64x64.
// Per K-tile: 4 phases x {stage 16KB unit || frag reads -> barrier ->
// setprio(1) 8xMFMA setprio(0) -> barrier}; counted vmcnt(2) once per K-tile
// (never 0 mid-loop). LDS 96KB double-buffered, 1 block/CU.
// MODE 0: C = acc*s + bias (+residual), fp32 row-major.
// MODE 1: u = acc*s + bias; a = silu(g)*u; out8 = quant(a/qscale), v2-A tiled.
template<int MODE>
__global__ __launch_bounds__(512, 2)
void gemm_i8p(const signed char* __restrict__ A8, const signed char* __restrict__ W8,
              const float* __restrict__ scale_ptr, const float* __restrict__ bias,
              const float* __restrict__ residual, float* __restrict__ C,
              const float* __restrict__ gbuf, const float* __restrict__ qscale,
              signed char* __restrict__ out8,
              const int N, const int K, const int gx)
{
    __shared__ __align__(16) signed char lsA[2][32768];
    __shared__ __align__(16) signed char lsB[2][16384];

    int bid = blockIdx.x;
    {   // bijective XCD chunked remap (m204)
        const int nwg = gridDim.x;
        const int q = nwg >> 3, r = nwg & 7;
        const int xcd = bid & 7, idx = bid >> 3;
        bid = (xcd < r) ? (xcd * (q + 1) + idx)
                        : (r * (q + 1) + (xcd - r) * q + idx);
    }
    const int bx = bid % gx, by = bid / gx;
    const int tid = threadIdx.x, lane = tid & 63, wid = tid >> 6;
    const int wr = wid >> 1, wc = wid & 1;
    const int bm = bx << 8, bn = by << 7;

    i32x4 acc[4][4];
#pragma unroll
    for (int m = 0; m < 4; ++m)
#pragma unroll
        for (int n = 0; n < 4; ++n) acc[m][n] = (i32x4){0, 0, 0, 0};

    const int nk = K >> 7;
    const signed char* abase = A8 + ((long)bx * nk << 15);
    const signed char* bbase = W8 + ((long)by * nk << 14);
    const int sgg = wid * 2048 + lane * 16;        // GLOBAL src: per-lane (r7 fix)
    const int sgl = wid * 2048;                    // LDS dest: wave-uniform
    // LDS frag read bases (v2 image): A half = wr>>1, row&127 = (wr&1)*64+m*16+fr
    const int la0 = (wr >> 1) * 16384 + (lane >> 4) * 2048
                  + ((wr & 1) * 64 + (lane & 15)) * 16;
    const int lb0 = (lane >> 4) * 2048 + (wc * 64 + (lane & 15)) * 16;

    // prologue: stage tile 0 (A: 2 units, B: 1 unit; 6 gloads/wave)
    gload_lds16(abase + sgg,                lsA[0] + sgl);
    gload_lds16(abase + sgg + 1024,         lsA[0] + sgl + 1024);
    gload_lds16(abase + 16384 + sgg,        lsA[0] + 16384 + sgl);
    gload_lds16(abase + 16384 + sgg + 1024, lsA[0] + 16384 + sgl + 1024);
    gload_lds16(bbase + sgg,                lsB[0] + sgl);
    gload_lds16(bbase + sgg + 1024,         lsB[0] + sgl + 1024);

    for (int kt = 0; kt < nk; ++kt) {
        const signed char* lA = lsA[kt & 1];
        const signed char* lB = lsB[kt & 1];
        signed char* nA = lsA[(kt & 1) ^ 1];
        signed char* nB = lsB[(kt & 1) ^ 1];
        const signed char* an = abase + ((long)(kt + 1) << 15);
        const signed char* wn = bbase + ((long)(kt + 1) << 14);
        const bool pf = (kt + 1 < nk);

        i32x4 af0, af1, af2, af3, bf0, bf1, bf2, bf3;

        // ---- phase 0: slice 0, n-frags {0,1}; stage next A-unit0; tile wait
        if (pf) {
            gload_lds16(an + sgg,        nA + sgl);
            gload_lds16(an + sgg + 1024, nA + sgl + 1024);
            asm volatile("s_waitcnt vmcnt(2)" ::: "memory");   // drain tile kt's 6
        } else {
            asm volatile("s_waitcnt vmcnt(0)" ::: "memory");
        }
        asm volatile("s_barrier" ::: "memory");    // tile kt visible to all
        af0 = *(const i32x4*)(lA + la0);
        af1 = *(const i32x4*)(lA + la0 + 256);
        af2 = *(const i32x4*)(lA + la0 + 512);
        af3 = *(const i32x4*)(lA + la0 + 768);
        bf0 = *(const i32x4*)(lB + lb0);
        bf1 = *(const i32x4*)(lB + lb0 + 256);
        __builtin_amdgcn_s_setprio(1);
        acc[0][0] = __builtin_amdgcn_mfma_i32_16x16x64_i8(af0, bf0, acc[0][0], 0, 0, 0);
        acc[1][0] = __builtin_amdgcn_mfma_i32_16x16x64_i8(af1, bf0, acc[1][0], 0, 0, 0);
        acc[2][0] = __builtin_amdgcn_mfma_i32_16x16x64_i8(af2, bf0, acc[2][0], 0, 0, 0);
        acc[3][0] = __builtin_amdgcn_mfma_i32_16x16x64_i8(af3, bf0, acc[3][0], 0, 0, 0);
        acc[0][1] = __builtin_amdgcn_mfma_i32_16x16x64_i8(af0, bf1, acc[0][1], 0, 0, 0);
        acc[1][1] = __builtin_amdgcn_mfma_i32_16x16x64_i8(af1, bf1, acc[1][1], 0, 0, 0);
        acc[2][1] = __builtin_amdgcn_mfma_i32_16x16x64_i8(af2, bf1, acc[2][1], 0, 0, 0);
        acc[3][1] = __builtin_amdgcn_mfma_i32_16x16x64_i8(af3, bf1, acc[3][1], 0, 0, 0);
        __builtin_amdgcn_s_setprio(0);
        asm volatile("s_barrier" ::: "memory");

        // ---- phase 1: slice 0, n-frags {2,3}; stage next A-unit1
        bf2 = *(const i32x4*)(lB + lb0 + 512);
        bf3 = *(const i32x4*)(lB + lb0 + 768);
        if (pf) {
            gload_lds16(an + 16384 + sgg,        nA + 16384 + sgl);
            gload_lds16(an + 16384 + sgg + 1024, nA + 16384 + sgl + 1024);
        }
        asm volatile("s_barrier" ::: "memory");
        __builtin_amdgcn_s_setprio(1);
        acc[0][2] = __builtin_amdgcn_mfma_i32_16x16x64_i8(af0, bf2, acc[0][2], 0, 0, 0);
        acc[1][2] = __builtin_amdgcn_mfma_i32_16x16x64_i8(af1, bf2, acc[1][2], 0, 0, 0);
        acc[2][2] = __builtin_amdgcn_mfma_i32_16x16x64_i8(af2, bf2, acc[2][2], 0, 0, 0);
        acc[3][2] = __builtin_amdgcn_mfma_i32_16x16x64_i8(af3, bf2, acc[3][2], 0, 0, 0);
        acc[0][3] = __builtin_amdgcn_mfma_i32_16x16x64_i8(af0, bf3, acc[0][3], 0, 0, 0);
        acc[1][3] = __builtin_amdgcn_mfma_i32_16x16x64_i8(af1, bf3, acc[1][3], 0, 0, 0);
        acc[2][3] = __builtin_amdgcn_mfma_i32_16x16x64_i8(af2, bf3, acc[2][3], 0, 0, 0);
        acc[3][3] = __builtin_amdgcn_mfma_i32_16x16x64_i8(af3, bf3, acc[3][3], 0, 0, 0);
        __builtin_amdgcn_s_setprio(0);
        asm volatile("s_barrier" ::: "memory");

        // ---- phase 2: slice 1, n-frags {0,1}; stage next B-unit
        af0 = *(const i32x4*)(lA + la0 + 8192);
        af1 = *(const i32x4*)(lA + la0 + 8192 + 256);
        af2 = *(const i32x4*)(lA + la0 + 8192 + 512);
        af3 = *(const i32x4*)(lA + la0 + 8192 + 768);
        bf0 = *(const i32x4*)(lB + lb0 + 8192);
        bf1 = *(const i32x4*)(lB + lb0 + 8192 + 256);
        if (pf) {
            gload_lds16(wn + sgg,        nB + sgl);
            gload_lds16(wn + sgg + 1024, nB + sgl + 1024);
        }
        asm volatile("s_barrier" ::: "memory");
        __builtin_amdgcn_s_setprio(1);
        acc[0][0] = __builtin_amdgcn_mfma_i32_16x16x64_i8(af0, bf0, acc[0][0], 0, 0, 0);
        acc[1][0] = __builtin_amdgcn_mfma_i32_16x16x64_i8(af1, bf0, acc[1][0], 0, 0, 0);
        acc[2][0] = __builtin_amdgcn_mfma_i32_16x16x64_i8(af2, bf0, acc[2][0], 0, 0, 0);
        acc[3][0] = __builtin_amdgcn_mfma_i32_16x16x64_i8(af3, bf0, acc[3][0], 0, 0, 0);
        acc[0][1] = __builtin_amdgcn_mfma_i32_16x16x64_i8(af0, bf1, acc[0][1], 0, 0, 0);
        acc[1][1] = __builtin_amdgcn_mfma_i32_16x16x64_i8(af1, bf1, acc[1][1], 0, 0, 0);
        acc[2][1] = __builtin_amdgcn_mfma_i32_16x16x64_i8(af2, bf1, acc[2][1], 0, 0, 0);
        acc[3][1] = __builtin_amdgcn_mfma_i32_16x16x64_i8(af3, bf1, acc[3][1], 0, 0, 0);
        __builtin_amdgcn_s_setprio(0);
        asm volatile("s_barrier" ::: "memory");

        // ---- phase 3: slice 1, n-frags {2,3}
        bf2 = *(const i32x4*)(lB + lb0 + 8192 + 512);
        bf3 = *(const i32x4*)(lB + lb0 + 8192 + 768);
        asm volatile("s_barrier" ::: "memory");
        __builtin_amdgcn_s_setprio(1);
        acc[0][2] = __builtin_amdgcn_mfma_i32_16x16x64_i8(af0, bf2, acc[0][2], 0, 0, 0);
        acc[1][2] = __builtin_amdgcn_mfma_i32_16x16x64_i8(af1, bf2, acc[1][2], 0, 0, 0);
        acc[2][2] = __builtin_amdgcn_mfma_i32_16x16x64_i8(af2, bf2, acc[2][2], 0, 0, 0);
        acc[3][2] = __builtin_amdgcn_mfma_i32_16x16x64_i8(af3, bf2, acc[3][2], 0, 0, 0);
        acc[0][3] = __builtin_amdgcn_mfma_i32_16x16x64_i8(af0, bf3, acc[0][3], 0, 0, 0);
        acc[1][3] = __builtin_amdgcn_mfma_i32_16x16x64_i8(af1, bf3, acc[1][3], 0, 0, 0);
        acc[2][3] = __builtin_amdgcn_mfma_i32_16x16x64_i8(af2, bf3, acc[2][3], 0, 0, 0);
        acc[3][3] = __builtin_amdgcn_mfma_i32_16x16x64_i8(af3, bf3, acc[3][3], 0, 0, 0);
        __builtin_amdgcn_s_setprio(0);
        asm volatile("s_barrier" ::: "memory");    // anti-WAR: buf free for stages
    }

    const float s = *scale_ptr;
    const int rq = (lane >> 4) * 4, fc = lane & 15;
    if (MODE == 0) {
#pragma unroll
        for (int m = 0; m < 4; ++m) {
#pragma unroll
            for (int n = 0; n < 4; ++n) {
                const int col = bn + wc * 64 + n * 16 + fc;
                const float bcol = bias[col];
#pragma unroll
                for (int r = 0; r < 4; ++r) {
                    const int row = bm + wr * 64 + m * 16 + rq + r;
                    float v = (float)acc[m][n][r] * s + bcol;
                    if (residual) v += residual[(long)row * N + col];
                    C[(long)row * N + col] = v;
                }
            }
        }
    } else {
        const float dinv = 1.f / qscale[0];
        const int nko = N >> 7;                    // v2-A tiling over N (=I)
#pragma unroll
        for (int m = 0; m < 4; ++m) {
#pragma unroll
            for (int n = 0; n < 4; ++n) {
                const int col = bn + wc * 64 + n * 16 + fc;
                const float bcol = bias[col];
                const int kt2 = col >> 7, sf = (col >> 6) & 1;
                const int kg2 = (col >> 4) & 3, jc = col & 15;
#pragma unroll
                for (int r = 0; r < 4; ++r) {
                    const int row = bm + wr * 64 + m * 16 + rq + r;
                    const float u = (float)acc[m][n][r] * s + bcol;
                    const float g = gbuf[(long)row * N + col];
                    const float a = g / (1.f + __expf(-g)) * u;
                    const float qv = fminf(fmaxf(rintf(a * dinv), -128.f), 127.f);
                    const long addr = (((long)(row >> 8) * nko + kt2) << 15)
                                    + ((long)((row >> 7) & 1) << 14)
                                    + (sf << 13) + (kg2 << 11)
                                    + ((row & 127) << 4) + jc;
                    out8[addr] = (signed char)(int)qv;
                }
            }
        }
    }
}

// ---------------------------------------------------------------------------
// RoPE applied in-place to q and k, layout [B,S,NH,HD] == [B,S,H] h-major.
__global__ __launch_bounds__(256)
void rope_k(float* __restrict__ q, float* __restrict__ k)
{
    const int row = blockIdx.x;            // token index b*S+s
    const int s = row & (S_ - 1);
    float* qr = q + (long)row * H_;
    float* kr = k + (long)row * H_;
    for (int t = threadIdx.x; t < NH_ * 64; t += 256) {
        const int nh = t >> 6, i = t & 63;
        const float inv = powf(10000.f, -(float)(2 * i) * (1.f / 128.f));
        const float f = (float)s * inv;
        float sn, c;
        sincosf(f, &sn, &c);
        const int base = nh * 128 + i;
        const float q0 = qr[base], q1 = qr[base + 64];
        qr[base]      = q0 * c - q1 * sn;
        qr[base + 64] = q1 * c + q0 * sn;
        const float k0 = kr[base], k1 = kr[base + 64];
        kr[base]      = k0 * c - k1 * sn;
        kr[base + 64] = k1 * c + k0 * sn;
    }
}

// ---------------------------------------------------------------------------
// Flash attention, bf16 MFMA; epilogue fuses o/o_in_scale quant -> v2-A tiled.
__global__ __launch_bounds__(256, 2)
void attn_mfma_k(const float* __restrict__ q, const float* __restrict__ k,
                 const float* __restrict__ v, signed char* __restrict__ out8,
                 const float* __restrict__ osc)
{
    __shared__ __align__(16) char lsK[8192];        // [32 krow][128 d] bf16, XOR swizzle
    __shared__ __align__(16) char lsV[10240];       // V^T [128 d][40 pitch] bf16
    __shared__ __align__(16) char lsP[4][1024];     // per-wave P [16][32] bf16, XOR swizzle

    const int tid = threadIdx.x, lane = tid & 63, wid = tid >> 6;
    const int bid = blockIdx.x;
    const int qt = 15 - (bid >> 6);                 // reversed: long blocks first
    const int bh = bid & 63;
    const int b = bh >> 5, h = bh & 31;
    const int q0 = qt * 64;
    const int qw = q0 + wid * 16;                   // this wave's first q row

    const float* qbase = q + (long)(b * S_) * H_ + (long)h * HD_;
    const float* kbase = k + (long)(b * S_) * H_ + (long)h * HD_;
    const float* vbase = v + (long)(b * S_) * H_ + (long)h * HD_;

    const int frow = lane & 15, fgrp = lane >> 4;
    const float sc = 0.08838834764831845f;          // 1/sqrt(128), folded into Q

    bf16x8 qf[4];
    {
        const float* qr = qbase + (long)(qw + frow) * H_;
#pragma unroll
        for (int c = 0; c < 4; ++c) {
            const float4 a = *(const float4*)(qr + c * 32 + fgrp * 8);
            const float4 bq = *(const float4*)(qr + c * 32 + fgrp * 8 + 4);
            bf16x8 t;
            t[0] = (short)f2bf(a.x * sc);  t[1] = (short)f2bf(a.y * sc);
            t[2] = (short)f2bf(a.z * sc);  t[3] = (short)f2bf(a.w * sc);
            t[4] = (short)f2bf(bq.x * sc); t[5] = (short)f2bf(bq.y * sc);
            t[6] = (short)f2bf(bq.z * sc); t[7] = (short)f2bf(bq.w * sc);
            qf[c] = t;
        }
    }

    f32x4 oacc[8];
#pragma unroll
    for (int n2 = 0; n2 < 8; ++n2) oacc[n2] = (f32x4){0.f, 0.f, 0.f, 0.f};
    float mr[4] = {-1e30f, -1e30f, -1e30f, -1e30f};
    float lr[4] = {0.f, 0.f, 0.f, 0.f};

    const int nt = (q0 >> 5) + 2;
    for (int kt = 0; kt < nt; ++kt) {
        if (kt) __syncthreads();
        {
            const float* kg = kbase + (long)(kt * 32) * H_;
            const float* vg = vbase + (long)(kt * 32) * H_;
#pragma unroll
            for (int i = 0; i < 4; ++i) {
                const int lin = i * 256 + tid;
                const int kr = lin >> 5;
                const int d4 = (lin & 31) * 4;
                const float4 kv = *(const float4*)(kg + (long)kr * H_ + d4);
                const float4 vv = *(const float4*)(vg + (long)kr * H_ + d4);
                ushort4 kb;
                kb.x = f2bf(kv.x); kb.y = f2bf(kv.y); kb.z = f2bf(kv.z); kb.w = f2bf(kv.w);
                *(ushort4*)(lsK + kr * 256 + ((d4 * 2) ^ ((kr & 7) << 4))) = kb;
                *(unsigned short*)(lsV + (d4 + 0) * 80 + kr * 2) = f2bf(vv.x);
                *(unsigned short*)(lsV + (d4 + 1) * 80 + kr * 2) = f2bf(vv.y);
                *(unsigned short*)(lsV + (d4 + 2) * 80 + kr * 2) = f2bf(vv.z);
                *(unsigned short*)(lsV + (d4 + 3) * 80 + kr * 2) = f2bf(vv.w);
            }
        }
        __syncthreads();

        if (kt * 32 <= qw + 15) {
            f32x4 s0 = (f32x4){0.f, 0.f, 0.f, 0.f};
            f32x4 s1 = (f32x4){0.f, 0.f, 0.f, 0.f};
            const int swz = (frow & 7) << 4;
#pragma unroll
            for (int c = 0; c < 4; ++c) {
                const int dby = c * 64 + fgrp * 16;
                const bf16x8 kfA = *(const bf16x8*)(lsK + frow * 256 + (dby ^ swz));
                const bf16x8 kfB = *(const bf16x8*)(lsK + (frow + 16) * 256 + (dby ^ swz));
                s0 = __builtin_amdgcn_mfma_f32_16x16x32_bf16(qf[c], kfA, s0, 0, 0, 0);
                s1 = __builtin_amdgcn_mfma_f32_16x16x32_bf16(qf[c], kfB, s1, 0, 0, 0);
            }

            const int colg0 = kt * 32 + frow;
            float cf[4];
#pragma unroll
            for (int r = 0; r < 4; ++r) {
                const int rowg = qw + fgrp * 4 + r;
                const float a0 = (colg0 <= rowg) ? s0[r] : -1e30f;
                const float a1 = (colg0 + 16 <= rowg) ? s1[r] : -1e30f;
                float mx = fmaxf(a0, a1);
#pragma unroll
                for (int off2 = 1; off2 < 16; off2 <<= 1) mx = fmaxf(mx, __shfl_xor(mx, off2));
                const float mnew = fmaxf(mr[r], mx);
                cf[r] = __expf(mr[r] - mnew);
                mr[r] = mnew;
                const float p0 = __expf(a0 - mnew);
                const float p1 = __expf(a1 - mnew);
                float sm = p0 + p1;
#pragma unroll
                for (int off2 = 1; off2 < 16; off2 <<= 1) sm += __shfl_xor(sm, off2);
                lr[r] = lr[r] * cf[r] + sm;
                const int row = fgrp * 4 + r;
                const int psw = (row & 3) << 4;
                *(unsigned short*)(lsP[wid] + row * 64 + ((frow * 2) ^ psw)) = f2bf(p0);
                *(unsigned short*)(lsP[wid] + row * 64 + (((16 + frow) * 2) ^ psw)) = f2bf(p1);
            }
#pragma unroll
            for (int n2 = 0; n2 < 8; ++n2) {
#pragma unroll
                for (int r = 0; r < 4; ++r) oacc[n2][r] *= cf[r];
            }
            const bf16x8 pf = *(const bf16x8*)(lsP[wid] + frow * 64 + ((fgrp * 16) ^ ((frow & 3) << 4)));
#pragma unroll
            for (int n2 = 0; n2 < 8; ++n2) {
                const bf16x8 vf = *(const bf16x8*)(lsV + (n2 * 16 + frow) * 80 + fgrp * 16);
                oacc[n2] = __builtin_amdgcn_mfma_f32_16x16x32_bf16(pf, vf, oacc[n2], 0, 0, 0);
            }
        }
    }

    // epilogue: o = oacc/l, q8 = clip(rint(o/osc)) -> v2-A tiled (nk128 = 32)
    const float oinv = 1.f / osc[0];
    float inv[4];
#pragma unroll
    for (int r = 0; r < 4; ++r) inv[r] = 1.f / lr[r];
#pragma unroll
    for (int n2 = 0; n2 < 8; ++n2) {
        const int kk = h * 128 + n2 * 16 + frow;
        const int kt2 = kk >> 7, sf = (kk >> 6) & 1, kg = (kk >> 4) & 3, jc = kk & 15;
#pragma unroll
        for (int r = 0; r < 4; ++r) {
            const int rowt = b * S_ + qw + fgrp * 4 + r;
            const float ov = oacc[n2][r] * inv[r];
            const float qv = fminf(fmaxf(rintf(ov * oinv), -128.f), 127.f);
            const long addr = (((long)(rowt >> 8) * 32 + kt2) << 15)
                            + ((long)((rowt >> 7) & 1) << 14)
                            + (sf << 13) + (kg << 11) + ((rowt & 127) << 4) + jc;
            out8[addr] = (signed char)(int)qv;
        }
    }
}

// ---------------------------------------------------------------------------
extern "C" void kernel_launch(void* const* d_in, const int* in_sizes, int n_in,
                              void* d_out, int out_size, void* d_ws, size_t ws_size,
                              hipStream_t stream)
{
    const float* hidden = (const float*)d_in[0];
    const float* ln1 = (const float*)d_in[1];
    const float* ln2 = (const float*)d_in[2];
    const int* Wq = (const int*)d_in[3];
    const int* Wk = (const int*)d_in[4];
    const int* Wv = (const int*)d_in[5];
    const int* Wo = (const int*)d_in[6];
    const int* Wg = (const int*)d_in[7];
    const int* Wu = (const int*)d_in[8];
    const int* Wd = (const int*)d_in[9];
    const float* bq = (const float*)d_in[10];
    const float* bk = (const float*)d_in[11];
    const float* bv = (const float*)d_in[12];
    const float* bo = (const float*)d_in[13];
    const float* bg = (const float*)d_in[14];
    const float* bu = (const float*)d_in[15];
    const float* bd = (const float*)d_in[16];
    const float* sq = (const float*)d_in[17];
    const float* sk = (const float*)d_in[18];
    const float* sv = (const float*)d_in[19];
    const float* so = (const float*)d_in[20];
    const float* sg = (const float*)d_in[21];
    const float* su = (const float*)d_in[22];
    const float* sd = (const float*)d_in[23];
    const float* o_sc = (const float*)d_in[24];
    const float* d_sc = (const float*)d_in[25];

    // workspace (MiB offsets, peak 206 MiB):
    //  [0,22)    HQ8 v2-A tiled int8 (hq / oq / hq2, sequential reuse)
    //  [22,66)   WP: packed-W scratch (max 43.01 MiB)
    //  [66,98)   Qb fp32 -> (post-attn) Hb
    //  [98,130)  Kb ; [130,162) Vb ; [98,184) Gb (after attn, K/V dead)
    //  [184,206) AQ8 v2-A tiled int8 (2048 x 11008)
    char* ws = (char*)d_ws;
    signed char* HQ8 = (signed char*)ws;
    signed char* WP  = (signed char*)(ws + ((size_t)22 << 20));
    float* Qb = (float*)(ws + ((size_t)66 << 20));
    float* Kb = (float*)(ws + ((size_t)98 << 20));
    float* Vb = (float*)(ws + ((size_t)130 << 20));
    float* Gb = (float*)(ws + ((size_t)98 << 20));
    signed char* AQ8 = (signed char*)(ws + ((size_t)184 << 20));
    float* Hb = Qb;
    float* out = (float*)d_out;

    const dim3 blk(256);
    const dim3 blk5(512);
    const int gxM = R_ / 256;                 // 8 row blocks
    const int nwgH = gxM * (H_ / 128);        // 256
    const int nwgI = gxM * (I_ / 128);        // 688
    const dim3 gpH(H_ / 128, H_ / 128);       // pack grids: (K/128, N/128)
    const dim3 gpI(H_ / 128, I_ / 128);
    const dim3 gpD(I_ / 128, H_ / 128);

    rmsnorm_quant_k<<<R_, blk, 0, stream>>>(hidden, ln1, HQ8);

    packW_k<<<gpH, blk, 0, stream>>>(Wq, WP, H_);
    gemm_i8p<0><<<nwgH, blk5, 0, stream>>>(HQ8, WP, sq, bq, nullptr, Qb,
                                           nullptr, nullptr, nullptr, H_, H_, gxM);
    packW_k<<<gpH, blk, 0, stream>>>(Wk, WP, H_);
    gemm_i8p<0><<<nwgH, blk5, 0, stream>>>(HQ8, WP, sk, bk, nullptr, Kb,
                                           nullptr, nullptr, nullptr, H_, H_, gxM);
    packW_k<<<gpH, blk, 0, stream>>>(Wv, WP, H_);
    gemm_i8p<0><<<nwgH, blk5, 0, stream>>>(HQ8, WP, sv, bv, nullptr, Vb,
                                           nullptr, nullptr, nullptr, H_, H_, gxM);

    rope_k<<<R_, blk, 0, stream>>>(Qb, Kb);
    attn_mfma_k<<<B_ * NH_ * (S_ / 64), blk, 0, stream>>>(Qb, Kb, Vb, HQ8, o_sc);

    packW_k<<<gpH, blk, 0, stream>>>(Wo, WP, H_);
    gemm_i8p<0><<<nwgH, blk5, 0, stream>>>(HQ8, WP, so, bo, hidden, Hb,
                                           nullptr, nullptr, nullptr, H_, H_, gxM);

    rmsnorm_quant_k<<<R_, blk, 0, stream>>>(Hb, ln2, HQ8);

    packW_k<<<gpI, blk, 0, stream>>>(Wg, WP, H_);
    gemm_i8p<0><<<nwgI, blk5, 0, stream>>>(HQ8, WP, sg, bg, nullptr, Gb,
                                           nullptr, nullptr, nullptr, I_, H_, gxM);
    packW_k<<<gpI, blk, 0, stream>>>(Wu, WP, H_);
    gemm_i8p<1><<<nwgI, blk5, 0, stream>>>(HQ8, WP, su, bu, nullptr, nullptr,
                                           Gb, d_sc, AQ8, I_, H_, gxM);
    packW_k<<<gpD, blk, 0, stream>>>(Wd, WP, I_);
    gemm_i8p<0><<<nwgH, blk5, 0, stream>>>(AQ8, WP, sd, bd, Hb, out,
                                           nullptr, nullptr, nullptr, H_, I_, gxM);
}

// Round 10
// 959.033 us; speedup vs baseline: 1.2016x; 1.2016x over previous
//
#include <hip/hip_runtime.h>
#include <math.h>

#define B_  2
#define S_  1024
#define H_  4096
#define NH_ 32
#define HD_ 128
#define I_  11008
#define R_  2048   // B*S tokens

typedef __attribute__((ext_vector_type(4))) int i32x4;
typedef __attribute__((ext_vector_type(4))) float f32x4;
typedef __attribute__((ext_vector_type(8))) short bf16x8;

// Tiled int8 layout (v1, validated): for matrix [Rows][K], nk = K/64;
// tile (rb, kt) is 8192 B at ((rb*nk + kt)<<13), internally
// [kgrp 0..3][row 0..127][16B]  (kgrp = (k%64)/16).

// ---------------------------------------------------------------------------
// global->LDS DMA. r7 LESSON: the GLOBAL src address is PER-LANE (must include
// lane*16); the LDS dest is wave-uniform, HW adds lane*16.
__device__ __forceinline__ void gload_lds16(const void* g, void* l) {
    __builtin_amdgcn_global_load_lds(
        (const __attribute__((address_space(1))) unsigned int*)g,
        (__attribute__((address_space(3))) unsigned int*)l, 16, 0, 0);
}

__device__ __forceinline__ unsigned short f2bf(float f) {
    unsigned int u = __float_as_uint(f);
    u += 0x7fffu + ((u >> 16) & 1u);   // RNE
    return (unsigned short)(u >> 16);
}

// ---------------------------------------------------------------------------
// Pack one W (int32 [N][K]) into tiled-i8. Grid: (K/64, N/128).
__global__ __launch_bounds__(256)
void packW_k(const int* __restrict__ W, signed char* __restrict__ out, const int K)
{
    const int kt = blockIdx.x, cb = blockIdx.y, nk = gridDim.x;
    const int t = threadIdx.x;
    int* otile = (int*)(out + ((long)(cb * nk + kt) << 13));
#pragma unroll
    for (int i = 0; i < 8; ++i) {
        const int o = i * 256 + t;                 // int32 index in tile
        const int g = o >> 9, r = (o >> 2) & 127, jj = o & 3;
        const int4 w4 = *(const int4*)(W + (long)(cb * 128 + r) * K + kt * 64 + g * 16 + jj * 4);
        otile[o] = (w4.x & 255) | ((w4.y & 255) << 8) | ((w4.z & 255) << 16) | (w4.w << 24);
    }
}

// ---------------------------------------------------------------------------
// RMSNorm + int8 quant (scale folded into w). Output in tiled-i8 (nk=64).
__global__ __launch_bounds__(256)
void rmsnorm_quant_k(const float* __restrict__ x, const float* __restrict__ w,
                     signed char* __restrict__ out)
{
    __shared__ float red[4];
    const int tid = threadIdx.x;
    const long row = blockIdx.x;
    const float4* xr = (const float4*)(x + row * H_);
    float4 xv[4];
    float ss = 0.f;
#pragma unroll
    for (int i = 0; i < 4; ++i) {
        xv[i] = xr[tid + i * 256];
        ss += xv[i].x * xv[i].x + xv[i].y * xv[i].y
            + xv[i].z * xv[i].z + xv[i].w * xv[i].w;
    }
#pragma unroll
    for (int off = 32; off; off >>= 1) ss += __shfl_xor(ss, off);
    if ((tid & 63) == 0) red[tid >> 6] = ss;
    __syncthreads();
    const float tot = red[0] + red[1] + red[2] + red[3];
    const float sc = 1.f / sqrtf(tot * (1.f / (float)H_) + 1e-6f);
    const float4* wr = (const float4*)w;
    int* ob = (int*)out;
    const long rb = row >> 7;
    const int rr = (int)(row & 127);
#pragma unroll
    for (int i = 0; i < 4; ++i) {
        const float4 wv = wr[tid + i * 256];
        const int b0 = (int)fminf(fmaxf(rintf(xv[i].x * sc * wv.x), -128.f), 127.f);
        const int b1 = (int)fminf(fmaxf(rintf(xv[i].y * sc * wv.y), -128.f), 127.f);
        const int b2 = (int)fminf(fmaxf(rintf(xv[i].z * sc * wv.z), -128.f), 127.f);
        const int b3 = (int)fminf(fmaxf(rintf(xv[i].w * sc * wv.w), -128.f), 127.f);
        const int packed = (b0 & 255) | ((b1 & 255) << 8) | ((b2 & 255) << 16) | (b3 << 24);
        const int j4 = tid + i * 256;              // int32 group within row
        const long a32 = ((rb * 64 + (j4 >> 4)) << 11) + (((j4 >> 2) & 3) << 9)
                       + (rr << 2) + (j4 & 3);
        ob[a32] = packed;
    }
}

// ---------------------------------------------------------------------------
// int8 GEMM (round-8 validated): BK=128 double-step, depth-2 ring, counted
// vmcnt(8), 64KB LDS -> 2 blocks/CU. Wave-out 64x64 (acc[4][4]).
// MODE 0: C = acc*s + bias (+residual), fp32 row-major.
template<int MODE>
__global__ __launch_bounds__(256, 2)
void gemm_i8t(const signed char* __restrict__ A8, const signed char* __restrict__ W8,
              const float* __restrict__ scale_ptr, const float* __restrict__ bias,
              const float* __restrict__ residual, float* __restrict__ C,
              const float* __restrict__ gbuf, const float* __restrict__ qscale,
              signed char* __restrict__ out8,
              const int N, const int K, const int gx)
{
    __shared__ __align__(16) signed char lsA[2][16384];
    __shared__ __align__(16) signed char lsB[2][16384];

    int bid = blockIdx.x;
    {   // bijective XCD chunked remap (m204)
        const int nwg = gridDim.x;
        const int q = nwg >> 3, r = nwg & 7;
        const int xcd = bid & 7, idx = bid >> 3;
        bid = (xcd < r) ? (xcd * (q + 1) + idx)
                        : (r * (q + 1) + (xcd - r) * q + idx);
    }
    const int bx = bid % gx, by = bid / gx;

    const int tid  = threadIdx.x;
    const int lane = tid & 63, wid = tid >> 6;
    const int bm = bx << 7, bn = by << 7;
    const int wm = (wid >> 1) << 6, wn = (wid & 1) << 6;

    i32x4 acc[4][4];
#pragma unroll
    for (int m = 0; m < 4; ++m)
#pragma unroll
        for (int n = 0; n < 4; ++n) acc[m][n] = (i32x4){0, 0, 0, 0};

    const int nk  = K >> 6;
    const int nk2 = K >> 7;
    const signed char* abase = A8 + ((long)bx * nk << 13);
    const signed char* bbase = W8 + ((long)by * nk << 13);
    const int sgg = wid * 4096 + lane * 16;        // GLOBAL src: per-lane
    const int sgl = wid * 4096;                    // LDS dest: wave-uniform

#pragma unroll
    for (int c = 0; c < 4; ++c) {
        gload_lds16(abase + sgg + c * 1024, lsA[0] + sgl + c * 1024);
        gload_lds16(bbase + sgg + c * 1024, lsB[0] + sgl + c * 1024);
    }

    for (int kt = 0; kt < nk2; ++kt) {
        const int cur = kt & 1, nxt = cur ^ 1;
        if (kt + 1 < nk2) {
            const signed char* at = abase + ((long)(kt + 1) << 14);
            const signed char* bt = bbase + ((long)(kt + 1) << 14);
#pragma unroll
            for (int c = 0; c < 4; ++c) {
                gload_lds16(at + sgg + c * 1024, lsA[nxt] + sgl + c * 1024);
                gload_lds16(bt + sgg + c * 1024, lsB[nxt] + sgl + c * 1024);
            }
            asm volatile("s_waitcnt vmcnt(8)" ::: "memory");
        } else {
            asm volatile("s_waitcnt vmcnt(0)" ::: "memory");
        }
        __builtin_amdgcn_s_barrier();

        const int kg = (lane >> 4) * 2048, fr = (lane & 15) * 16;
#pragma unroll
        for (int s = 0; s < 2; ++s) {
            const int off = s * 8192;
            i32x4 af[4], bf[4];
#pragma unroll
            for (int m = 0; m < 4; ++m)
                af[m] = *(const i32x4*)(lsA[cur] + off + kg + wm * 16 + m * 256 + fr);
#pragma unroll
            for (int n = 0; n < 4; ++n)
                bf[n] = *(const i32x4*)(lsB[cur] + off + kg + wn * 16 + n * 256 + fr);
            __builtin_amdgcn_s_setprio(1);
#pragma unroll
            for (int m = 0; m < 4; ++m)
#pragma unroll
                for (int n = 0; n < 4; ++n)
                    acc[m][n] = __builtin_amdgcn_mfma_i32_16x16x64_i8(af[m], bf[n], acc[m][n], 0, 0, 0);
            __builtin_amdgcn_s_setprio(0);
        }
        __builtin_amdgcn_s_barrier();
    }

    const float s = *scale_ptr;
    const int rq = (lane >> 4) * 4, fc = lane & 15;
#pragma unroll
    for (int m = 0; m < 4; ++m) {
#pragma unroll
        for (int n = 0; n < 4; ++n) {
            const int col = bn + wn + n * 16 + fc;
            const float bcol = bias[col];
#pragma unroll
            for (int r = 0; r < 4; ++r) {
                const int row = bm + wm + m * 16 + rq + r;
                float v = (float)acc[m][n][r] * s + bcol;
                if (residual) v += residual[(long)row * N + col];
                C[(long)row * N + col] = v;
            }
        }
    }
}

// ---------------------------------------------------------------------------
// Wide-tile int8 GEMM for the I-GEMMs (Wg, Wu): BM=128, BN=256, BK=64,
// wave-out 64x128 (acc[4][8]) -> 12 frag-reads per 32 MFMA (-25% LDS traffic
// vs gemm_i8t's 16/32). Same validated sync skeleton: issue next step ->
// counted vmcnt(6) -> barrier -> frag reads + MFMA -> barrier. 48KB LDS.
// MODE 0: C = acc*s + bias, fp32. MODE 1: silu(g)*u -> quant -> v1-A tiled.
template<int MODE>
__global__ __launch_bounds__(256, 2)
void gemm_i8w(const signed char* __restrict__ A8, const signed char* __restrict__ W8,
              const float* __restrict__ scale_ptr, const float* __restrict__ bias,
              float* __restrict__ C,
              const float* __restrict__ gbuf, const float* __restrict__ qscale,
              signed char* __restrict__ out8,
              const int N, const int K, const int gx)
{
    __shared__ __align__(16) signed char lsA[2][8192];
    __shared__ __align__(16) signed char lsB[2][16384];

    int bid = blockIdx.x;
    {   // bijective XCD chunked remap
        const int nwg = gridDim.x;
        const int q = nwg >> 3, r = nwg & 7;
        const int xcd = bid & 7, idx = bid >> 3;
        bid = (xcd < r) ? (xcd * (q + 1) + idx)
                        : (r * (q + 1) + (xcd - r) * q + idx);
    }
    const int bx = bid % gx, by = bid / gx;
    const int tid = threadIdx.x, lane = tid & 63, wid = tid >> 6;
    const int bm = bx << 7, bn = by << 8;
    const int wm = (wid >> 1) << 6;                // 0 / 64 rows
    const int wn = (wid & 1) << 7;                 // 0 / 128 cols

    i32x4 acc[4][8];
#pragma unroll
    for (int m = 0; m < 4; ++m)
#pragma unroll
        for (int n = 0; n < 8; ++n) acc[m][n] = (i32x4){0, 0, 0, 0};

    const int nk = K >> 6;
    const signed char* abase = A8 + ((long)bx * nk << 13);
    const signed char* bbase = W8 + ((long)(2 * by) * nk << 13);
    // A staging: wave stages [wid*2KB, +2KB) of 8KB tile (2 gloads)
    const int sa = wid * 2048;
    // B staging: wave stages [wid*4KB, +4KB) of 16KB (tile0||tile1) (4 gloads)
    const int sb = wid * 4096;

    // prologue: stage step 0 (6 gloads/wave)
    {
        gload_lds16(abase + sa + lane * 16,        lsA[0] + sa);
        gload_lds16(abase + sa + lane * 16 + 1024, lsA[0] + sa + 1024);
#pragma unroll
        for (int c = 0; c < 4; ++c) {
            const int o = sb + c * 1024;           // offset in 16KB concat
            const long gsrc = ((long)((o >> 13) * nk) << 13) + (o & 8191);
            gload_lds16(bbase + gsrc + lane * 16, lsB[0] + o);
        }
    }

    for (int kt = 0; kt < nk; ++kt) {
        const int cur = kt & 1, nxt = cur ^ 1;
        if (kt + 1 < nk) {
            const signed char* at = abase + ((long)(kt + 1) << 13);
            gload_lds16(at + sa + lane * 16,        lsA[nxt] + sa);
            gload_lds16(at + sa + lane * 16 + 1024, lsA[nxt] + sa + 1024);
#pragma unroll
            for (int c = 0; c < 4; ++c) {
                const int o = sb + c * 1024;
                const long gsrc = ((long)((o >> 13) * nk + (kt + 1)) << 13) + (o & 8191);
                gload_lds16(bbase + gsrc + lane * 16, lsB[nxt] + o);
            }
            asm volatile("s_waitcnt vmcnt(6)" ::: "memory");   // drain step kt's 6
        } else {
            asm volatile("s_waitcnt vmcnt(0)" ::: "memory");
        }
        __builtin_amdgcn_s_barrier();              // step kt visible

        const int kg = (lane >> 4) * 2048, fr = (lane & 15) * 16;
        const int bofs = (wid & 1) * 8192;         // which 128-col tile
        i32x4 af[4], bf[8];
#pragma unroll
        for (int m = 0; m < 4; ++m)
            af[m] = *(const i32x4*)(lsA[cur] + kg + wm * 16 + m * 256 + fr);
#pragma unroll
        for (int n = 0; n < 8; ++n)
            bf[n] = *(const i32x4*)(lsB[cur] + bofs + kg + n * 256 + fr);
        __builtin_amdgcn_s_setprio(1);
#pragma unroll
        for (int m = 0; m < 4; ++m)
#pragma unroll
            for (int n = 0; n < 8; ++n)
                acc[m][n] = __builtin_amdgcn_mfma_i32_16x16x64_i8(af[m], bf[n], acc[m][n], 0, 0, 0);
        __builtin_amdgcn_s_setprio(0);
        __builtin_amdgcn_s_barrier();              // buf[cur] free
    }

    const float s = *scale_ptr;
    const int rq = (lane >> 4) * 4, fc = lane & 15;
    if (MODE == 0) {
#pragma unroll
        for (int m = 0; m < 4; ++m) {
#pragma unroll
            for (int n = 0; n < 8; ++n) {
                const int col = bn + wn + n * 16 + fc;
                const float bcol = bias[col];
#pragma unroll
                for (int r = 0; r < 4; ++r) {
                    const int row = bm + wm + m * 16 + rq + r;
                    C[(long)row * N + col] = (float)acc[m][n][r] * s + bcol;
                }
            }
        }
    } else {
        const float dinv = 1.f / qscale[0];
        const int nko = N >> 6;                    // v1-A tiling over N (=I)
#pragma unroll
        for (int m = 0; m < 4; ++m) {
#pragma unroll
            for (int n = 0; n < 8; ++n) {
                const int col = bn + wn + n * 16 + fc;
                const float bcol = bias[col];
                const int ktc = col >> 6, kgc = (col >> 4) & 3, jc = col & 15;
#pragma unroll
                for (int r = 0; r < 4; ++r) {
                    const int row = bm + wm + m * 16 + rq + r;
                    const float u = (float)acc[m][n][r] * s + bcol;
                    const float g = gbuf[(long)row * N + col];
                    const float a = g / (1.f + __expf(-g)) * u;
                    const float qv = fminf(fmaxf(rintf(a * dinv), -128.f), 127.f);
                    const long addr = (((long)(row >> 7) * nko + ktc) << 13)
                                    + (kgc << 11) + ((row & 127) << 4) + jc;
                    out8[addr] = (signed char)(int)qv;
                }
            }
        }
    }
}

// ---------------------------------------------------------------------------
// RoPE applied in-place to q and k, layout [B,S,NH,HD] == [B,S,H] h-major.
__global__ __launch_bounds__(256)
void rope_k(float* __restrict__ q, float* __restrict__ k)
{
    const int row = blockIdx.x;            // token index b*S+s
    const int s = row & (S_ - 1);
    float* qr = q + (long)row * H_;
    float* kr = k + (long)row * H_;
    for (int t = threadIdx.x; t < NH_ * 64; t += 256) {
        const int nh = t >> 6, i = t & 63;
        const float inv = powf(10000.f, -(float)(2 * i) * (1.f / 128.f));
        const float f = (float)s * inv;
        float sn, c;
        sincosf(f, &sn, &c);
        const int base = nh * 128 + i;
        const float q0 = qr[base], q1 = qr[base + 64];
        qr[base]      = q0 * c - q1 * sn;
        qr[base + 64] = q1 * c + q0 * sn;
        const float k0 = kr[base], k1 = kr[base + 64];
        kr[base]      = k0 * c - k1 * sn;
        kr[base + 64] = k1 * c + k0 * sn;
    }
}

// ---------------------------------------------------------------------------
// Flash attention, bf16 MFMA; epilogue fuses o/o_in_scale quant -> tiled-i8.
// (256,3): 3 blocks/CU -> 1024 blocks in 1.33 rounds instead of 2.
__global__ __launch_bounds__(256, 3)
void attn_mfma_k(const float* __restrict__ q, const float* __restrict__ k,
                 const float* __restrict__ v, signed char* __restrict__ out8,
                 const float* __restrict__ osc)
{
    __shared__ __align__(16) char lsK[8192];        // [32 krow][128 d] bf16, XOR swizzle
    __shared__ __align__(16) char lsV[10240];       // V^T [128 d][40 pitch] bf16
    __shared__ __align__(16) char lsP[4][1024];     // per-wave P [16][32] bf16, XOR swizzle

    const int tid = threadIdx.x, lane = tid & 63, wid = tid >> 6;
    const int bid = blockIdx.x;
    const int qt = 15 - (bid >> 6);                 // reversed: long blocks first
    const int bh = bid & 63;
    const int b = bh >> 5, h = bh & 31;
    const int q0 = qt * 64;
    const int qw = q0 + wid * 16;                   // this wave's first q row

    const float* qbase = q + (long)(b * S_) * H_ + (long)h * HD_;
    const float* kbase = k + (long)(b * S_) * H_ + (long)h * HD_;
    const float* vbase = v + (long)(b * S_) * H_ + (long)h * HD_;

    const int frow = lane & 15, fgrp = lane >> 4;
    const float sc = 0.08838834764831845f;          // 1/sqrt(128), folded into Q

    bf16x8 qf[4];
    {
        const float* qr = qbase + (long)(qw + frow) * H_;
#pragma unroll
        for (int c = 0; c < 4; ++c) {
            const float4 a = *(const float4*)(qr + c * 32 + fgrp * 8);
            const float4 bq = *(const float4*)(qr + c * 32 + fgrp * 8 + 4);
            bf16x8 t;
            t[0] = (short)f2bf(a.x * sc);  t[1] = (short)f2bf(a.y * sc);
            t[2] = (short)f2bf(a.z * sc);  t[3] = (short)f2bf(a.w * sc);
            t[4] = (short)f2bf(bq.x * sc); t[5] = (short)f2bf(bq.y * sc);
            t[6] = (short)f2bf(bq.z * sc); t[7] = (short)f2bf(bq.w * sc);
            qf[c] = t;
        }
    }

    f32x4 oacc[8];
#pragma unroll
    for (int n2 = 0; n2 < 8; ++n2) oacc[n2] = (f32x4){0.f, 0.f, 0.f, 0.f};
    float mr[4] = {-1e30f, -1e30f, -1e30f, -1e30f};
    float lr[4] = {0.f, 0.f, 0.f, 0.f};

    const int nt = (q0 >> 5) + 2;
    for (int kt = 0; kt < nt; ++kt) {
        if (kt) __syncthreads();
        {
            const float* kg = kbase + (long)(kt * 32) * H_;
            const float* vg = vbase + (long)(kt * 32) * H_;
#pragma unroll
            for (int i = 0; i < 4; ++i) {
                const int lin = i * 256 + tid;
                const int kr = lin >> 5;
                const int d4 = (lin & 31) * 4;
                const float4 kv = *(const float4*)(kg + (long)kr * H_ + d4);
                const float4 vv = *(const float4*)(vg + (long)kr * H_ + d4);
                ushort4 kb;
                kb.x = f2bf(kv.x); kb.y = f2bf(kv.y); kb.z = f2bf(kv.z); kb.w = f2bf(kv.w);
                *(ushort4*)(lsK + kr * 256 + ((d4 * 2) ^ ((kr & 7) << 4))) = kb;
                *(unsigned short*)(lsV + (d4 + 0) * 80 + kr * 2) = f2bf(vv.x);
                *(unsigned short*)(lsV + (d4 + 1) * 80 + kr * 2) = f2bf(vv.y);
                *(unsigned short*)(lsV + (d4 + 2) * 80 + kr * 2) = f2bf(vv.z);
                *(unsigned short*)(lsV + (d4 + 3) * 80 + kr * 2) = f2bf(vv.w);
            }
        }
        __syncthreads();

        if (kt * 32 <= qw + 15) {
            f32x4 s0 = (f32x4){0.f, 0.f, 0.f, 0.f};
            f32x4 s1 = (f32x4){0.f, 0.f, 0.f, 0.f};
            const int swz = (frow & 7) << 4;
#pragma unroll
            for (int c = 0; c < 4; ++c) {
                const int dby = c * 64 + fgrp * 16;
                const bf16x8 kfA = *(const bf16x8*)(lsK + frow * 256 + (dby ^ swz));
                const bf16x8 kfB = *(const bf16x8*)(lsK + (frow + 16) * 256 + (dby ^ swz));
                s0 = __builtin_amdgcn_mfma_f32_16x16x32_bf16(qf[c], kfA, s0, 0, 0, 0);
                s1 = __builtin_amdgcn_mfma_f32_16x16x32_bf16(qf[c], kfB, s1, 0, 0, 0);
            }

            const int colg0 = kt * 32 + frow;
            float cf[4];
#pragma unroll
            for (int r = 0; r < 4; ++r) {
                const int rowg = qw + fgrp * 4 + r;
                const float a0 = (colg0 <= rowg) ? s0[r] : -1e30f;
                const float a1 = (colg0 + 16 <= rowg) ? s1[r] : -1e30f;
                float mx = fmaxf(a0, a1);
#pragma unroll
                for (int off2 = 1; off2 < 16; off2 <<= 1) mx = fmaxf(mx, __shfl_xor(mx, off2));
                const float mnew = fmaxf(mr[r], mx);
                cf[r] = __expf(mr[r] - mnew);
                mr[r] = mnew;
                const float p0 = __expf(a0 - mnew);
                const float p1 = __expf(a1 - mnew);
                float sm = p0 + p1;
#pragma unroll
                for (int off2 = 1; off2 < 16; off2 <<= 1) sm += __shfl_xor(sm, off2);
                lr[r] = lr[r] * cf[r] + sm;
                const int row = fgrp * 4 + r;
                const int psw = (row & 3) << 4;
                *(unsigned short*)(lsP[wid] + row * 64 + ((frow * 2) ^ psw)) = f2bf(p0);
                *(unsigned short*)(lsP[wid] + row * 64 + (((16 + frow) * 2) ^ psw)) = f2bf(p1);
            }
#pragma unroll
            for (int n2 = 0; n2 < 8; ++n2) {
#pragma unroll
                for (int r = 0; r < 4; ++r) oacc[n2][r] *= cf[r];
            }
            const bf16x8 pf = *(const bf16x8*)(lsP[wid] + frow * 64 + ((fgrp * 16) ^ ((frow & 3) << 4)));
#pragma unroll
            for (int n2 = 0; n2 < 8; ++n2) {
                const bf16x8 vf = *(const bf16x8*)(lsV + (n2 * 16 + frow) * 80 + fgrp * 16);
                oacc[n2] = __builtin_amdgcn_mfma_f32_16x16x32_bf16(pf, vf, oacc[n2], 0, 0, 0);
            }
        }
    }

    // epilogue: o = oacc/l, q8 = clip(rint(o/osc)) -> tiled-i8 (nk = 64)
    const float oinv = 1.f / osc[0];
    float inv[4];
#pragma unroll
    for (int r = 0; r < 4; ++r) inv[r] = 1.f / lr[r];
#pragma unroll
    for (int n2 = 0; n2 < 8; ++n2) {
        const int kk = h * 128 + n2 * 16 + frow;
        const int ktc = kk >> 6, kgc = (kk >> 4) & 3, jc = kk & 15;
#pragma unroll
        for (int r = 0; r < 4; ++r) {
            const int rowt = b * S_ + qw + fgrp * 4 + r;
            const float ov = oacc[n2][r] * inv[r];
            const float qv = fminf(fmaxf(rintf(ov * oinv), -128.f), 127.f);
            const long addr = (((long)(rowt >> 7) * 64 + ktc) << 13)
                            + (kgc << 11) + ((rowt & 127) << 4) + jc;
            out8[addr] = (signed char)(int)qv;
        }
    }
}

// ---------------------------------------------------------------------------
extern "C" void kernel_launch(void* const* d_in, const int* in_sizes, int n_in,
                              void* d_out, int out_size, void* d_ws, size_t ws_size,
                              hipStream_t stream)
{
    const float* hidden = (const float*)d_in[0];
    const float* ln1 = (const float*)d_in[1];
    const float* ln2 = (const float*)d_in[2];
    const int* Wq = (const int*)d_in[3];
    const int* Wk = (const int*)d_in[4];
    const int* Wv = (const int*)d_in[5];
    const int* Wo = (const int*)d_in[6];
    const int* Wg = (const int*)d_in[7];
    const int* Wu = (const int*)d_in[8];
    const int* Wd = (const int*)d_in[9];
    const float* bq = (const float*)d_in[10];
    const float* bk = (const float*)d_in[11];
    const float* bv = (const float*)d_in[12];
    const float* bo = (const float*)d_in[13];
    const float* bg = (const float*)d_in[14];
    const float* bu = (const float*)d_in[15];
    const float* bd = (const float*)d_in[16];
    const float* sq = (const float*)d_in[17];
    const float* sk = (const float*)d_in[18];
    const float* sv = (const float*)d_in[19];
    const float* so = (const float*)d_in[20];
    const float* sg = (const float*)d_in[21];
    const float* su = (const float*)d_in[22];
    const float* sd = (const float*)d_in[23];
    const float* o_sc = (const float*)d_in[24];
    const float* d_sc = (const float*)d_in[25];

    // workspace (MiB offsets, peak 206 MiB):
    //  [0,22)    A8 tiled int8: hq / oq / hq2 (8 MiB each, sequential reuse)
    //  [22,66)   WP: packed-W scratch (max 43.01 MiB)
    //  [66,98)   Qb fp32 -> (post-attn) Hb
    //  [98,130)  Kb ; [130,162) Vb ; [98,184) Gb (after attn, K/V dead)
    //  [184,206) AQ8 tiled int8 (2048 x 11008)
    char* ws = (char*)d_ws;
    signed char* HQ8 = (signed char*)ws;
    signed char* WP  = (signed char*)(ws + ((size_t)22 << 20));
    float* Qb = (float*)(ws + ((size_t)66 << 20));
    float* Kb = (float*)(ws + ((size_t)98 << 20));
    float* Vb = (float*)(ws + ((size_t)130 << 20));
    float* Gb = (float*)(ws + ((size_t)98 << 20));
    signed char* AQ8 = (signed char*)(ws + ((size_t)184 << 20));
    float* Hb = Qb;
    float* out = (float*)d_out;

    const dim3 blk(256);
    const int gxH = R_ / 128;                 // 16 row blocks
    const int nwgH = gxH * (H_ / 128);        // 512
    const int nwgW = gxH * (I_ / 256);        // 688 (wide-tile I-GEMMs)
    const dim3 gpH(H_ / 64, H_ / 128);        // pack grids: (nk, N/128)
    const dim3 gpI(H_ / 64, I_ / 128);
    const dim3 gpD(I_ / 64, H_ / 128);

    rmsnorm_quant_k<<<R_, blk, 0, stream>>>(hidden, ln1, HQ8);

    packW_k<<<gpH, blk, 0, stream>>>(Wq, WP, H_);
    gemm_i8t<0><<<nwgH, blk, 0, stream>>>(HQ8, WP, sq, bq, nullptr, Qb,
                                          nullptr, nullptr, nullptr, H_, H_, gxH);
    packW_k<<<gpH, blk, 0, stream>>>(Wk, WP, H_);
    gemm_i8t<0><<<nwgH, blk, 0, stream>>>(HQ8, WP, sk, bk, nullptr, Kb,
                                          nullptr, nullptr, nullptr, H_, H_, gxH);
    packW_k<<<gpH, blk, 0, stream>>>(Wv, WP, H_);
    gemm_i8t<0><<<nwgH, blk, 0, stream>>>(HQ8, WP, sv, bv, nullptr, Vb,
                                          nullptr, nullptr, nullptr, H_, H_, gxH);

    rope_k<<<R_, blk, 0, stream>>>(Qb, Kb);
    attn_mfma_k<<<B_ * NH_ * (S_ / 64), blk, 0, stream>>>(Qb, Kb, Vb, HQ8, o_sc);

    packW_k<<<gpH, blk, 0, stream>>>(Wo, WP, H_);
    gemm_i8t<0><<<nwgH, blk, 0, stream>>>(HQ8, WP, so, bo, hidden, Hb,
                                          nullptr, nullptr, nullptr, H_, H_, gxH);

    rmsnorm_quant_k<<<R_, blk, 0, stream>>>(Hb, ln2, HQ8);

    packW_k<<<gpI, blk, 0, stream>>>(Wg, WP, H_);
    gemm_i8w<0><<<nwgW, blk, 0, stream>>>(HQ8, WP, sg, bg, Gb,
                                          nullptr, nullptr, nullptr, I_, H_, gxH);
    packW_k<<<gpI, blk, 0, stream>>>(Wu, WP, H_);
    gemm_i8w<1><<<nwgW, blk, 0, stream>>>(HQ8, WP, su, bu, nullptr,
                                          Gb, d_sc, AQ8, I_, H_, gxH);
    packW_k<<<gpD, blk, 0, stream>>>(Wd, WP, I_);
    gemm_i8t<0><<<nwgH, blk, 0, stream>>>(AQ8, WP, sd, bd, Hb, out,
                                          nullptr, nullptr, nullptr, H_, I_, gxH);
}

// Round 11
// 932.298 us; speedup vs baseline: 1.2360x; 1.0287x over previous
//
#include <hip/hip_runtime.h>
#include <math.h>

#define B_  2
#define S_  1024
#define H_  4096
#define NH_ 32
#define HD_ 128
#define I_  11008
#define R_  2048   // B*S tokens

typedef __attribute__((ext_vector_type(4))) int i32x4;
typedef __attribute__((ext_vector_type(4))) float f32x4;
typedef __attribute__((ext_vector_type(8))) short bf16x8;

// Tiled int8 layout (v1, validated): for matrix [Rows][K], nk = K/64;
// tile (rb, kt) is 8192 B at ((rb*nk + kt)<<13), internally
// [kgrp 0..3][row 0..127][16B]  (kgrp = (k%64)/16).

// ---------------------------------------------------------------------------
// global->LDS DMA. r7 LESSON: the GLOBAL src address is PER-LANE (must include
// lane*16); the LDS dest is wave-uniform, HW adds lane*16.
__device__ __forceinline__ void gload_lds16(const void* g, void* l) {
    __builtin_amdgcn_global_load_lds(
        (const __attribute__((address_space(1))) unsigned int*)g,
        (__attribute__((address_space(3))) unsigned int*)l, 16, 0, 0);
}

__device__ __forceinline__ unsigned short f2bf(float f) {
    unsigned int u = __float_as_uint(f);
    u += 0x7fffu + ((u >> 16) & 1u);   // RNE
    return (unsigned short)(u >> 16);
}

// ---------------------------------------------------------------------------
// Pack one W (int32 [N][K]) into tiled-i8. Grid: (K/64, N/128).
__global__ __launch_bounds__(256)
void packW_k(const int* __restrict__ W, signed char* __restrict__ out, const int K)
{
    const int kt = blockIdx.x, cb = blockIdx.y, nk = gridDim.x;
    const int t = threadIdx.x;
    int* otile = (int*)(out + ((long)(cb * nk + kt) << 13));
#pragma unroll
    for (int i = 0; i < 8; ++i) {
        const int o = i * 256 + t;                 // int32 index in tile
        const int g = o >> 9, r = (o >> 2) & 127, jj = o & 3;
        const int4 w4 = *(const int4*)(W + (long)(cb * 128 + r) * K + kt * 64 + g * 16 + jj * 4);
        otile[o] = (w4.x & 255) | ((w4.y & 255) << 8) | ((w4.z & 255) << 16) | (w4.w << 24);
    }
}

// ---------------------------------------------------------------------------
// RMSNorm + int8 quant (scale folded into w). Output in tiled-i8 (nk=64).
__global__ __launch_bounds__(256)
void rmsnorm_quant_k(const float* __restrict__ x, const float* __restrict__ w,
                     signed char* __restrict__ out)
{
    __shared__ float red[4];
    const int tid = threadIdx.x;
    const long row = blockIdx.x;
    const float4* xr = (const float4*)(x + row * H_);
    float4 xv[4];
    float ss = 0.f;
#pragma unroll
    for (int i = 0; i < 4; ++i) {
        xv[i] = xr[tid + i * 256];
        ss += xv[i].x * xv[i].x + xv[i].y * xv[i].y
            + xv[i].z * xv[i].z + xv[i].w * xv[i].w;
    }
#pragma unroll
    for (int off = 32; off; off >>= 1) ss += __shfl_xor(ss, off);
    if ((tid & 63) == 0) red[tid >> 6] = ss;
    __syncthreads();
    const float tot = red[0] + red[1] + red[2] + red[3];
    const float sc = 1.f / sqrtf(tot * (1.f / (float)H_) + 1e-6f);
    const float4* wr = (const float4*)w;
    int* ob = (int*)out;
    const long rb = row >> 7;
    const int rr = (int)(row & 127);
#pragma unroll
    for (int i = 0; i < 4; ++i) {
        const float4 wv = wr[tid + i * 256];
        const int b0 = (int)fminf(fmaxf(rintf(xv[i].x * sc * wv.x), -128.f), 127.f);
        const int b1 = (int)fminf(fmaxf(rintf(xv[i].y * sc * wv.y), -128.f), 127.f);
        const int b2 = (int)fminf(fmaxf(rintf(xv[i].z * sc * wv.z), -128.f), 127.f);
        const int b3 = (int)fminf(fmaxf(rintf(xv[i].w * sc * wv.w), -128.f), 127.f);
        const int packed = (b0 & 255) | ((b1 & 255) << 8) | ((b2 & 255) << 16) | (b3 << 24);
        const int j4 = tid + i * 256;              // int32 group within row
        const long a32 = ((rb * 64 + (j4 >> 4)) << 11) + (((j4 >> 2) & 3) << 9)
                       + (rr << 2) + (j4 & 3);
        ob[a32] = packed;
    }
}

// ---------------------------------------------------------------------------
// int8 GEMM (round-8 validated): BK=128 double-step, depth-2 ring, counted
// vmcnt(8), 64KB LDS -> 2 blocks/CU. Wave-out 64x64 (acc[4][4]).
// MODE 0: C = acc*s + bias (+residual), fp32 row-major.
template<int MODE>
__global__ __launch_bounds__(256, 2)
void gemm_i8t(const signed char* __restrict__ A8, const signed char* __restrict__ W8,
              const float* __restrict__ scale_ptr, const float* __restrict__ bias,
              const float* __restrict__ residual, float* __restrict__ C,
              const int N, const int K, const int gx)
{
    __shared__ __align__(16) signed char lsA[2][16384];
    __shared__ __align__(16) signed char lsB[2][16384];

    int bid = blockIdx.x;
    {   // bijective XCD chunked remap (m204)
        const int nwg = gridDim.x;
        const int q = nwg >> 3, r = nwg & 7;
        const int xcd = bid & 7, idx = bid >> 3;
        bid = (xcd < r) ? (xcd * (q + 1) + idx)
                        : (r * (q + 1) + (xcd - r) * q + idx);
    }
    const int bx = bid % gx, by = bid / gx;

    const int tid  = threadIdx.x;
    const int lane = tid & 63, wid = tid >> 6;
    const int bm = bx << 7, bn = by << 7;
    const int wm = (wid >> 1) << 6, wn = (wid & 1) << 6;

    i32x4 acc[4][4];
#pragma unroll
    for (int m = 0; m < 4; ++m)
#pragma unroll
        for (int n = 0; n < 4; ++n) acc[m][n] = (i32x4){0, 0, 0, 0};

    const int nk  = K >> 6;
    const int nk2 = K >> 7;
    const signed char* abase = A8 + ((long)bx * nk << 13);
    const signed char* bbase = W8 + ((long)by * nk << 13);
    const int sgg = wid * 4096 + lane * 16;        // GLOBAL src: per-lane
    const int sgl = wid * 4096;                    // LDS dest: wave-uniform

#pragma unroll
    for (int c = 0; c < 4; ++c) {
        gload_lds16(abase + sgg + c * 1024, lsA[0] + sgl + c * 1024);
        gload_lds16(bbase + sgg + c * 1024, lsB[0] + sgl + c * 1024);
    }

    for (int kt = 0; kt < nk2; ++kt) {
        const int cur = kt & 1, nxt = cur ^ 1;
        if (kt + 1 < nk2) {
            const signed char* at = abase + ((long)(kt + 1) << 14);
            const signed char* bt = bbase + ((long)(kt + 1) << 14);
#pragma unroll
            for (int c = 0; c < 4; ++c) {
                gload_lds16(at + sgg + c * 1024, lsA[nxt] + sgl + c * 1024);
                gload_lds16(bt + sgg + c * 1024, lsB[nxt] + sgl + c * 1024);
            }
            asm volatile("s_waitcnt vmcnt(8)" ::: "memory");
        } else {
            asm volatile("s_waitcnt vmcnt(0)" ::: "memory");
        }
        __builtin_amdgcn_s_barrier();

        const int kg = (lane >> 4) * 2048, fr = (lane & 15) * 16;
#pragma unroll
        for (int s = 0; s < 2; ++s) {
            const int off = s * 8192;
            i32x4 af[4], bf[4];
#pragma unroll
            for (int m = 0; m < 4; ++m)
                af[m] = *(const i32x4*)(lsA[cur] + off + kg + wm * 16 + m * 256 + fr);
#pragma unroll
            for (int n = 0; n < 4; ++n)
                bf[n] = *(const i32x4*)(lsB[cur] + off + kg + wn * 16 + n * 256 + fr);
            __builtin_amdgcn_s_setprio(1);
#pragma unroll
            for (int m = 0; m < 4; ++m)
#pragma unroll
                for (int n = 0; n < 4; ++n)
                    acc[m][n] = __builtin_amdgcn_mfma_i32_16x16x64_i8(af[m], bf[n], acc[m][n], 0, 0, 0);
            __builtin_amdgcn_s_setprio(0);
        }
        __builtin_amdgcn_s_barrier();
    }

    const float s = *scale_ptr;
    const int rq = (lane >> 4) * 4, fc = lane & 15;
#pragma unroll
    for (int m = 0; m < 4; ++m) {
#pragma unroll
        for (int n = 0; n < 4; ++n) {
            const int col = bn + wn + n * 16 + fc;
            const float bcol = bias[col];
#pragma unroll
            for (int r = 0; r < 4; ++r) {
                const int row = bm + wm + m * 16 + rq + r;
                float v = (float)acc[m][n][r] * s + bcol;
                if (residual) v += residual[(long)row * N + col];
                C[(long)row * N + col] = v;
            }
        }
    }
}

// ---------------------------------------------------------------------------
// Fused gate+up int8 GEMM: one block computes both g and u 128x128 tiles over
// the SAME staged A-tile, then silu(g)*u -> quant -> AQ8 (v1-A tiled) in the
// epilogue. Kills the 90MB fp32 Gb write+read and halves A staging.
// Sync skeleton = r8-validated: issue 6 gloads -> vmcnt(6) -> barrier ->
// frag reads + 32 MFMA (setprio) -> barrier. 48KB LDS -> 2 blocks/CU.
__global__ __launch_bounds__(256, 2)
void gemm_gu(const signed char* __restrict__ A8, const signed char* __restrict__ G8,
             const signed char* __restrict__ U8,
             const float* __restrict__ sg_p, const float* __restrict__ bg,
             const float* __restrict__ su_p, const float* __restrict__ bu,
             const float* __restrict__ qscale, signed char* __restrict__ out8,
             const int N, const int K, const int gx)
{
    __shared__ __align__(16) signed char lsA[2][8192];
    __shared__ __align__(16) signed char lsG[2][8192];
    __shared__ __align__(16) signed char lsU[2][8192];

    int bid = blockIdx.x;
    {   // bijective XCD chunked remap
        const int nwg = gridDim.x;
        const int q = nwg >> 3, r = nwg & 7;
        const int xcd = bid & 7, idx = bid >> 3;
        bid = (xcd < r) ? (xcd * (q + 1) + idx)
                        : (r * (q + 1) + (xcd - r) * q + idx);
    }
    const int bx = bid % gx, by = bid / gx;
    const int tid = threadIdx.x, lane = tid & 63, wid = tid >> 6;
    const int bm = bx << 7, bn = by << 7;
    const int wm = (wid >> 1) << 6, wn = (wid & 1) << 6;

    i32x4 ag[4][4], au[4][4];
#pragma unroll
    for (int m = 0; m < 4; ++m)
#pragma unroll
        for (int n = 0; n < 4; ++n) {
            ag[m][n] = (i32x4){0, 0, 0, 0};
            au[m][n] = (i32x4){0, 0, 0, 0};
        }

    const int nk = K >> 6;
    const signed char* abase = A8 + ((long)bx * nk << 13);
    const signed char* gbase = G8 + ((long)by * nk << 13);
    const signed char* ubase = U8 + ((long)by * nk << 13);
    const int sgg = wid * 2048 + lane * 16;        // GLOBAL src: per-lane
    const int sgl = wid * 2048;                    // LDS dest: wave-uniform

    // prologue: stage step 0 (6 gloads/wave)
#pragma unroll
    for (int c = 0; c < 2; ++c) {
        gload_lds16(abase + sgg + c * 1024, lsA[0] + sgl + c * 1024);
        gload_lds16(gbase + sgg + c * 1024, lsG[0] + sgl + c * 1024);
        gload_lds16(ubase + sgg + c * 1024, lsU[0] + sgl + c * 1024);
    }

    for (int kt = 0; kt < nk; ++kt) {
        const int cur = kt & 1, nxt = cur ^ 1;
        if (kt + 1 < nk) {
            const signed char* at = abase + ((long)(kt + 1) << 13);
            const signed char* gt = gbase + ((long)(kt + 1) << 13);
            const signed char* ut = ubase + ((long)(kt + 1) << 13);
#pragma unroll
            for (int c = 0; c < 2; ++c) {
                gload_lds16(at + sgg + c * 1024, lsA[nxt] + sgl + c * 1024);
                gload_lds16(gt + sgg + c * 1024, lsG[nxt] + sgl + c * 1024);
                gload_lds16(ut + sgg + c * 1024, lsU[nxt] + sgl + c * 1024);
            }
            asm volatile("s_waitcnt vmcnt(6)" ::: "memory");   // drain step kt's 6
        } else {
            asm volatile("s_waitcnt vmcnt(0)" ::: "memory");
        }
        __builtin_amdgcn_s_barrier();              // step kt visible

        const int kg = (lane >> 4) * 2048, fr = (lane & 15) * 16;
        i32x4 af[4], gf[4], uf[4];
#pragma unroll
        for (int m = 0; m < 4; ++m)
            af[m] = *(const i32x4*)(lsA[cur] + kg + wm * 16 + m * 256 + fr);
#pragma unroll
        for (int n = 0; n < 4; ++n) {
            gf[n] = *(const i32x4*)(lsG[cur] + kg + wn * 16 + n * 256 + fr);
            uf[n] = *(const i32x4*)(lsU[cur] + kg + wn * 16 + n * 256 + fr);
        }
        __builtin_amdgcn_s_setprio(1);
#pragma unroll
        for (int m = 0; m < 4; ++m)
#pragma unroll
            for (int n = 0; n < 4; ++n) {
                ag[m][n] = __builtin_amdgcn_mfma_i32_16x16x64_i8(af[m], gf[n], ag[m][n], 0, 0, 0);
                au[m][n] = __builtin_amdgcn_mfma_i32_16x16x64_i8(af[m], uf[n], au[m][n], 0, 0, 0);
            }
        __builtin_amdgcn_s_setprio(0);
        __builtin_amdgcn_s_barrier();              // buf[cur] free
    }

    // epilogue: g = ag*sg + bg; u = au*su + bu; a = silu(g)*u; quant -> v1-A
    const float sg = *sg_p, su = *su_p;
    const float dinv = 1.f / qscale[0];
    const int nko = N >> 6;
    const int rq = (lane >> 4) * 4, fc = lane & 15;
#pragma unroll
    for (int m = 0; m < 4; ++m) {
#pragma unroll
        for (int n = 0; n < 4; ++n) {
            const int col = bn + wn + n * 16 + fc;
            const float bgc = bg[col], buc = bu[col];
            const int ktc = col >> 6, kgc = (col >> 4) & 3, jc = col & 15;
#pragma unroll
            for (int r = 0; r < 4; ++r) {
                const int row = bm + wm + m * 16 + rq + r;
                const float g = (float)ag[m][n][r] * sg + bgc;
                const float u = (float)au[m][n][r] * su + buc;
                const float a = g / (1.f + __expf(-g)) * u;
                const float qv = fminf(fmaxf(rintf(a * dinv), -128.f), 127.f);
                const long addr = (((long)(row >> 7) * nko + ktc) << 13)
                                + (kgc << 11) + ((row & 127) << 4) + jc;
                out8[addr] = (signed char)(int)qv;
            }
        }
    }
}

// ---------------------------------------------------------------------------
// RoPE applied in-place to q and k, layout [B,S,NH,HD] == [B,S,H] h-major.
__global__ __launch_bounds__(256)
void rope_k(float* __restrict__ q, float* __restrict__ k)
{
    const int row = blockIdx.x;            // token index b*S+s
    const int s = row & (S_ - 1);
    float* qr = q + (long)row * H_;
    float* kr = k + (long)row * H_;
    for (int t = threadIdx.x; t < NH_ * 64; t += 256) {
        const int nh = t >> 6, i = t & 63;
        const float inv = powf(10000.f, -(float)(2 * i) * (1.f / 128.f));
        const float f = (float)s * inv;
        float sn, c;
        sincosf(f, &sn, &c);
        const int base = nh * 128 + i;
        const float q0 = qr[base], q1 = qr[base + 64];
        qr[base]      = q0 * c - q1 * sn;
        qr[base + 64] = q1 * c + q0 * sn;
        const float k0 = kr[base], k1 = kr[base + 64];
        kr[base]      = k0 * c - k1 * sn;
        kr[base + 64] = k1 * c + k0 * sn;
    }
}

// ---------------------------------------------------------------------------
// Flash attention, bf16 MFMA; epilogue fuses o/o_in_scale quant -> tiled-i8.
__global__ __launch_bounds__(256, 3)
void attn_mfma_k(const float* __restrict__ q, const float* __restrict__ k,
                 const float* __restrict__ v, signed char* __restrict__ out8,
                 const float* __restrict__ osc)
{
    __shared__ __align__(16) char lsK[8192];        // [32 krow][128 d] bf16, XOR swizzle
    __shared__ __align__(16) char lsV[10240];       // V^T [128 d][40 pitch] bf16
    __shared__ __align__(16) char lsP[4][1024];     // per-wave P [16][32] bf16, XOR swizzle

    const int tid = threadIdx.x, lane = tid & 63, wid = tid >> 6;
    const int bid = blockIdx.x;
    const int qt = 15 - (bid >> 6);                 // reversed: long blocks first
    const int bh = bid & 63;
    const int b = bh >> 5, h = bh & 31;
    const int q0 = qt * 64;
    const int qw = q0 + wid * 16;                   // this wave's first q row

    const float* qbase = q + (long)(b * S_) * H_ + (long)h * HD_;
    const float* kbase = k + (long)(b * S_) * H_ + (long)h * HD_;
    const float* vbase = v + (long)(b * S_) * H_ + (long)h * HD_;

    const int frow = lane & 15, fgrp = lane >> 4;
    const float sc = 0.08838834764831845f;          // 1/sqrt(128), folded into Q

    bf16x8 qf[4];
    {
        const float* qr = qbase + (long)(qw + frow) * H_;
#pragma unroll
        for (int c = 0; c < 4; ++c) {
            const float4 a = *(const float4*)(qr + c * 32 + fgrp * 8);
            const float4 bq = *(const float4*)(qr + c * 32 + fgrp * 8 + 4);
            bf16x8 t;
            t[0] = (short)f2bf(a.x * sc);  t[1] = (short)f2bf(a.y * sc);
            t[2] = (short)f2bf(a.z * sc);  t[3] = (short)f2bf(a.w * sc);
            t[4] = (short)f2bf(bq.x * sc); t[5] = (short)f2bf(bq.y * sc);
            t[6] = (short)f2bf(bq.z * sc); t[7] = (short)f2bf(bq.w * sc);
            qf[c] = t;
        }
    }

    f32x4 oacc[8];
#pragma unroll
    for (int n2 = 0; n2 < 8; ++n2) oacc[n2] = (f32x4){0.f, 0.f, 0.f, 0.f};
    float mr[4] = {-1e30f, -1e30f, -1e30f, -1e30f};
    float lr[4] = {0.f, 0.f, 0.f, 0.f};

    const int nt = (q0 >> 5) + 2;
    for (int kt = 0; kt < nt; ++kt) {
        if (kt) __syncthreads();
        {
            const float* kg = kbase + (long)(kt * 32) * H_;
            const float* vg = vbase + (long)(kt * 32) * H_;
#pragma unroll
            for (int i = 0; i < 4; ++i) {
                const int lin = i * 256 + tid;
                const int kr = lin >> 5;
                const int d4 = (lin & 31) * 4;
                const float4 kv = *(const float4*)(kg + (long)kr * H_ + d4);
                const float4 vv = *(const float4*)(vg + (long)kr * H_ + d4);
                ushort4 kb;
                kb.x = f2bf(kv.x); kb.y = f2bf(kv.y); kb.z = f2bf(kv.z); kb.w = f2bf(kv.w);
                *(ushort4*)(lsK + kr * 256 + ((d4 * 2) ^ ((kr & 7) << 4))) = kb;
                *(unsigned short*)(lsV + (d4 + 0) * 80 + kr * 2) = f2bf(vv.x);
                *(unsigned short*)(lsV + (d4 + 1) * 80 + kr * 2) = f2bf(vv.y);
                *(unsigned short*)(lsV + (d4 + 2) * 80 + kr * 2) = f2bf(vv.z);
                *(unsigned short*)(lsV + (d4 + 3) * 80 + kr * 2) = f2bf(vv.w);
            }
        }
        __syncthreads();

        if (kt * 32 <= qw + 15) {
            f32x4 s0 = (f32x4){0.f, 0.f, 0.f, 0.f};
            f32x4 s1 = (f32x4){0.f, 0.f, 0.f, 0.f};
            const int swz = (frow & 7) << 4;
#pragma unroll
            for (int c = 0; c < 4; ++c) {
                const int dby = c * 64 + fgrp * 16;
                const bf16x8 kfA = *(const bf16x8*)(lsK + frow * 256 + (dby ^ swz));
                const bf16x8 kfB = *(const bf16x8*)(lsK + (frow + 16) * 256 + (dby ^ swz));
                s0 = __builtin_amdgcn_mfma_f32_16x16x32_bf16(qf[c], kfA, s0, 0, 0, 0);
                s1 = __builtin_amdgcn_mfma_f32_16x16x32_bf16(qf[c], kfB, s1, 0, 0, 0);
            }

            const int colg0 = kt * 32 + frow;
            float cf[4];
#pragma unroll
            for (int r = 0; r < 4; ++r) {
                const int rowg = qw + fgrp * 4 + r;
                const float a0 = (colg0 <= rowg) ? s0[r] : -1e30f;
                const float a1 = (colg0 + 16 <= rowg) ? s1[r] : -1e30f;
                float mx = fmaxf(a0, a1);
#pragma unroll
                for (int off2 = 1; off2 < 16; off2 <<= 1) mx = fmaxf(mx, __shfl_xor(mx, off2));
                const float mnew = fmaxf(mr[r], mx);
                cf[r] = __expf(mr[r] - mnew);
                mr[r] = mnew;
                const float p0 = __expf(a0 - mnew);
                const float p1 = __expf(a1 - mnew);
                float sm = p0 + p1;
#pragma unroll
                for (int off2 = 1; off2 < 16; off2 <<= 1) sm += __shfl_xor(sm, off2);
                lr[r] = lr[r] * cf[r] + sm;
                const int row = fgrp * 4 + r;
                const int psw = (row & 3) << 4;
                *(unsigned short*)(lsP[wid] + row * 64 + ((frow * 2) ^ psw)) = f2bf(p0);
                *(unsigned short*)(lsP[wid] + row * 64 + (((16 + frow) * 2) ^ psw)) = f2bf(p1);
            }
#pragma unroll
            for (int n2 = 0; n2 < 8; ++n2) {
#pragma unroll
                for (int r = 0; r < 4; ++r) oacc[n2][r] *= cf[r];
            }
            const bf16x8 pf = *(const bf16x8*)(lsP[wid] + frow * 64 + ((fgrp * 16) ^ ((frow & 3) << 4)));
#pragma unroll
            for (int n2 = 0; n2 < 8; ++n2) {
                const bf16x8 vf = *(const bf16x8*)(lsV + (n2 * 16 + frow) * 80 + fgrp * 16);
                oacc[n2] = __builtin_amdgcn_mfma_f32_16x16x32_bf16(pf, vf, oacc[n2], 0, 0, 0);
            }
        }
    }

    // epilogue: o = oacc/l, q8 = clip(rint(o/osc)) -> tiled-i8 (nk = 64)
    const float oinv = 1.f / osc[0];
    float inv[4];
#pragma unroll
    for (int r = 0; r < 4; ++r) inv[r] = 1.f / lr[r];
#pragma unroll
    for (int n2 = 0; n2 < 8; ++n2) {
        const int kk = h * 128 + n2 * 16 + frow;
        const int ktc = kk >> 6, kgc = (kk >> 4) & 3, jc = kk & 15;
#pragma unroll
        for (int r = 0; r < 4; ++r) {
            const int rowt = b * S_ + qw + fgrp * 4 + r;
            const float ov = oacc[n2][r] * inv[r];
            const float qv = fminf(fmaxf(rintf(ov * oinv), -128.f), 127.f);
            const long addr = (((long)(rowt >> 7) * 64 + ktc) << 13)
                            + (kgc << 11) + ((rowt & 127) << 4) + jc;
            out8[addr] = (signed char)(int)qv;
        }
    }
}

// ---------------------------------------------------------------------------
extern "C" void kernel_launch(void* const* d_in, const int* in_sizes, int n_in,
                              void* d_out, int out_size, void* d_ws, size_t ws_size,
                              hipStream_t stream)
{
    const float* hidden = (const float*)d_in[0];
    const float* ln1 = (const float*)d_in[1];
    const float* ln2 = (const float*)d_in[2];
    const int* Wq = (const int*)d_in[3];
    const int* Wk = (const int*)d_in[4];
    const int* Wv = (const int*)d_in[5];
    const int* Wo = (const int*)d_in[6];
    const int* Wg = (const int*)d_in[7];
    const int* Wu = (const int*)d_in[8];
    const int* Wd = (const int*)d_in[9];
    const float* bq = (const float*)d_in[10];
    const float* bk = (const float*)d_in[11];
    const float* bv = (const float*)d_in[12];
    const float* bo = (const float*)d_in[13];
    const float* bg = (const float*)d_in[14];
    const float* bu = (const float*)d_in[15];
    const float* bd = (const float*)d_in[16];
    const float* sq = (const float*)d_in[17];
    const float* sk = (const float*)d_in[18];
    const float* sv = (const float*)d_in[19];
    const float* so = (const float*)d_in[20];
    const float* sg = (const float*)d_in[21];
    const float* su = (const float*)d_in[22];
    const float* sd = (const float*)d_in[23];
    const float* o_sc = (const float*)d_in[24];
    const float* d_sc = (const float*)d_in[25];

    // workspace (MiB offsets, peak 206 MiB):
    //  [0,22)    A8 tiled int8: hq / oq / hq2 (8 MiB each, sequential reuse)
    //  [22,66)   WP: packed-W scratch (Wq/Wk/Wv/Wo/Wg/Wd sequential, max 43 MiB)
    //  [66,98)   Qb fp32 -> (post-attn) Hb
    //  [98,130)  Kb ; [130,162) Vb ; [98,141) WPu (after attn, K/V dead)
    //  [184,206) AQ8 tiled int8 (2048 x 11008)
    char* ws = (char*)d_ws;
    signed char* HQ8 = (signed char*)ws;
    signed char* WP  = (signed char*)(ws + ((size_t)22 << 20));
    float* Qb = (float*)(ws + ((size_t)66 << 20));
    float* Kb = (float*)(ws + ((size_t)98 << 20));
    float* Vb = (float*)(ws + ((size_t)130 << 20));
    signed char* WPu = (signed char*)(ws + ((size_t)98 << 20));
    signed char* AQ8 = (signed char*)(ws + ((size_t)184 << 20));
    float* Hb = Qb;
    float* out = (float*)d_out;

    const dim3 blk(256);
    const int gxH = R_ / 128;                 // 16 row blocks
    const int nwgH = gxH * (H_ / 128);        // 512
    const int nwgI = gxH * (I_ / 128);        // 1376
    const dim3 gpH(H_ / 64, H_ / 128);        // pack grids: (nk, N/128)
    const dim3 gpI(H_ / 64, I_ / 128);
    const dim3 gpD(I_ / 64, H_ / 128);

    rmsnorm_quant_k<<<R_, blk, 0, stream>>>(hidden, ln1, HQ8);

    packW_k<<<gpH, blk, 0, stream>>>(Wq, WP, H_);
    gemm_i8t<0><<<nwgH, blk, 0, stream>>>(HQ8, WP, sq, bq, nullptr, Qb, H_, H_, gxH);
    packW_k<<<gpH, blk, 0, stream>>>(Wk, WP, H_);
    gemm_i8t<0><<<nwgH, blk, 0, stream>>>(HQ8, WP, sk, bk, nullptr, Kb, H_, H_, gxH);
    packW_k<<<gpH, blk, 0, stream>>>(Wv, WP, H_);
    gemm_i8t<0><<<nwgH, blk, 0, stream>>>(HQ8, WP, sv, bv, nullptr, Vb, H_, H_, gxH);

    rope_k<<<R_, blk, 0, stream>>>(Qb, Kb);
    attn_mfma_k<<<B_ * NH_ * (S_ / 64), blk, 0, stream>>>(Qb, Kb, Vb, HQ8, o_sc);

    packW_k<<<gpH, blk, 0, stream>>>(Wo, WP, H_);
    gemm_i8t<0><<<nwgH, blk, 0, stream>>>(HQ8, WP, so, bo, hidden, Hb, H_, H_, gxH);

    rmsnorm_quant_k<<<R_, blk, 0, stream>>>(Hb, ln2, HQ8);

    packW_k<<<gpI, blk, 0, stream>>>(Wg, WP, H_);
    packW_k<<<gpI, blk, 0, stream>>>(Wu, WPu, H_);
    gemm_gu<<<nwgI, blk, 0, stream>>>(HQ8, WP, WPu, sg, bg, su, bu,
                                      d_sc, AQ8, I_, H_, gxH);
    packW_k<<<gpD, blk, 0, stream>>>(Wd, WP, I_);
    gemm_i8t<0><<<nwgH, blk, 0, stream>>>(AQ8, WP, sd, bd, Hb, out, H_, I_, gxH);
}